// Round 1
// baseline (344.392 us; speedup 1.0000x reference)
//
#include <hip/hip_runtime.h>
#include <math.h>

// Problem constants (fixed by setup_inputs)
#define BATCH 32768
#define SS 16          // bands / sequence
#define DI 14          // input dim
#define BQ 256         // stored patterns
#define NC 7           // classes
#define NBLK 4096      // main-kernel grid

// ws layout:
//   kpack : double2[7][256]   (28672 B)  LN_st(lookup) packed as dim-pairs x pattern
//   Tf    : float[256*7]      ( 7168 B)  per-pattern class contribution table
//   zb    : double[7]         (   56 B)  bm[c]*sum(Wb) + bb
#define WS_KPACK_OFF 0
#define WS_TF_OFF    28672
#define WS_ZB_OFF    (28672 + 7168)

__global__ __launch_bounds__(256) void precompute_kernel(
    const float* __restrict__ lookup,
    const float* __restrict__ g_st, const float* __restrict__ b_st,
    const float* __restrict__ g_pp, const float* __restrict__ b_pp,
    const float* __restrict__ Wv,  const float* __restrict__ Wo,
    const float* __restrict__ Wm,  const float* __restrict__ bm,
    const float* __restrict__ Wb,  const float* __restrict__ bb,
    double2* __restrict__ kpack, float* __restrict__ Tf, double* __restrict__ zb)
{
    __shared__ double G1s[256][7];   // (Wo.T @ Wm.T)  : [p][c]
    __shared__ double Gs[14][7];     // Wv.T @ G1      : [d][c]
    const int tid = threadIdx.x;

    // G1[p][c] = sum_o Wo[o,p] * Wm[c,o]
    {
        const int p = tid;
        for (int c = 0; c < NC; ++c) {
            double acc = 0.0;
            for (int o = 0; o < 28; ++o)
                acc += (double)Wo[o * 256 + p] * (double)Wm[c * 28 + o];
            G1s[p][c] = acc;
        }
    }
    __syncthreads();
    // G[d][c] = sum_p Wv[p,d] * G1[p][c]
    if (tid < DI * NC) {
        const int d = tid / NC, c = tid % NC;
        double acc = 0.0;
        for (int p = 0; p < 256; ++p)
            acc += (double)Wv[p * DI + d] * G1s[p][c];
        Gs[d][c] = acc;
    }
    __syncthreads();

    // Per stored pattern j: LayerNorm once (shared mu/var), emit k (fp64) and T row.
    {
        const int j = tid;
        double xr[DI];
        double sum = 0.0;
        for (int d = 0; d < DI; ++d) { xr[d] = (double)lookup[j * DI + d]; sum += xr[d]; }
        const double mu = sum * (1.0 / (double)DI);
        double vs = 0.0;
        for (int d = 0; d < DI; ++d) { const double t = xr[d] - mu; vs += t * t; }
        const double rs = 1.0 / sqrt(vs * (1.0 / (double)DI) + 1e-5);

        double kj[DI], vl[DI];
        for (int d = 0; d < DI; ++d) {
            const double nrm = (xr[d] - mu) * rs;
            kj[d] = nrm * (double)g_st[d] + (double)b_st[d];
            vl[d] = nrm * (double)g_pp[d] + (double)b_pp[d];
        }
        for (int d2 = 0; d2 < DI / 2; ++d2) {
            double2 kv; kv.x = kj[2 * d2]; kv.y = kj[2 * d2 + 1];
            kpack[d2 * 256 + j] = kv;
        }
        for (int c = 0; c < NC; ++c) {
            double acc = 0.0;
            for (int d = 0; d < DI; ++d) acc += vl[d] * Gs[d][c];
            Tf[j * NC + c] = (float)acc;
        }
    }
    if (tid < NC) {
        double wbsum = 0.0;
        for (int s = 0; s < SS; ++s) wbsum += (double)Wb[s];
        zb[tid] = (double)bm[tid] * wbsum + (double)bb[0];
    }
}

__global__ __launch_bounds__(256) void hopfield_kernel(
    const float* __restrict__ x,
    const float* __restrict__ g_sp, const float* __restrict__ b_sp,
    const double2* __restrict__ kpack, const float* __restrict__ Tf,
    const double* __restrict__ zb, const float* __restrict__ Wb,
    float* __restrict__ out)
{
    __shared__ double2 kps[7 * 256];            // 28672 B, [d2][j] -> b128 bank-floor reads
    __shared__ float   Ts[256 * NC];            //  7168 B
    __shared__ __align__(16) double qsh[SS * DI];  // 1792 B, LN'd state rows
    __shared__ int    jstar[SS];
    __shared__ double zrow[NC];

    const int tid  = threadIdx.x;
    const int lane = tid & 63;
    const int w    = tid >> 6;

    for (int i = tid; i < 7 * 256; i += 256) kps[i] = kpack[i];
    for (int i = tid; i < 256 * NC; i += 256) Ts[i] = Tf[i];
    __syncthreads();

    const double2* qsh2 = (const double2*)qsh;

    for (int b = blockIdx.x; b < BATCH; b += gridDim.x) {
        // LayerNorm the 16 state rows cooperatively (fp64)
        if (tid < SS) {
            const int s = tid;
            const float* xr = x + ((size_t)b * SS + s) * DI;
            double xv[DI]; double sum = 0.0;
            for (int d = 0; d < DI; ++d) { xv[d] = (double)xr[d]; sum += xv[d]; }
            const double mu = sum * (1.0 / (double)DI);
            double vs = 0.0;
            for (int d = 0; d < DI; ++d) { const double t = xv[d] - mu; vs += t * t; }
            const double rs = 1.0 / sqrt(vs * (1.0 / (double)DI) + 1e-5);
            for (int d = 0; d < DI; ++d)
                qsh[s * DI + d] = (xv[d] - mu) * rs * (double)g_sp[d] + (double)b_sp[d];
        }
        __syncthreads();

        // Each wave: 4 rows, processed 2 at a time (k reuse across rows).
        for (int it = 0; it < 2; ++it) {
            const int s0 = w * 4 + it * 2;
            double q0[DI], q1[DI];
            for (int d2 = 0; d2 < 7; ++d2) {
                const double2 a  = qsh2[s0 * 7 + d2];
                const double2 bq = qsh2[(s0 + 1) * 7 + d2];
                q0[2 * d2] = a.x;  q0[2 * d2 + 1] = a.y;
                q1[2 * d2] = bq.x; q1[2 * d2 + 1] = bq.y;
            }
            double best0 = -1e300, best1 = -1e300;
            int bj0 = 0, bj1 = 0;
            for (int jj = 0; jj < 4; ++jj) {
                const int j = jj * 64 + lane;
                double a0 = 0.0, a1 = 0.0;
                for (int d2 = 0; d2 < 7; ++d2) {
                    const double2 kv = kps[d2 * 256 + j];
                    a0 += q0[2 * d2] * kv.x; a0 += q0[2 * d2 + 1] * kv.y;
                    a1 += q1[2 * d2] * kv.x; a1 += q1[2 * d2 + 1] * kv.y;
                }
                if (a0 > best0) { best0 = a0; bj0 = j; }
                if (a1 > best1) { best1 = a1; bj1 = j; }
            }
            // wave-wide argmax (lowest index on exact ties)
            for (int off = 32; off > 0; off >>= 1) {
                const double ov0 = __shfl_down(best0, off);
                const int    oj0 = __shfl_down(bj0, off);
                const double ov1 = __shfl_down(best1, off);
                const int    oj1 = __shfl_down(bj1, off);
                if (ov0 > best0 || (ov0 == best0 && oj0 < bj0)) { best0 = ov0; bj0 = oj0; }
                if (ov1 > best1 || (ov1 == best1 && oj1 < bj1)) { best1 = ov1; bj1 = oj1; }
            }
            if (lane == 0) { jstar[s0] = bj0; jstar[s0 + 1] = bj1; }
        }
        __syncthreads();

        // Head: z[c] = zb[c] + sum_s Wb[s] * T[jstar[s], c]; then softmax over 7.
        if (tid < NC) {
            double z = zb[tid];
            for (int s = 0; s < SS; ++s)
                z += (double)Wb[s] * (double)Ts[jstar[s] * NC + tid];
            zrow[tid] = z;
        }
        __syncthreads();
        if (tid < NC) {
            double m = zrow[0];
            for (int c = 1; c < NC; ++c) m = fmax(m, zrow[c]);
            double den = 0.0;
            for (int c = 0; c < NC; ++c) den += exp(zrow[c] - m);
            out[(size_t)b * NC + tid] = (float)(exp(zrow[tid] - m) / den);
        }
        __syncthreads();
    }
}

extern "C" void kernel_launch(void* const* d_in, const int* in_sizes, int n_in,
                              void* d_out, int out_size, void* d_ws, size_t ws_size,
                              hipStream_t stream) {
    const float* x      = (const float*)d_in[0];
    const float* lookup = (const float*)d_in[1];
    const float* g_st   = (const float*)d_in[2];
    const float* b_st   = (const float*)d_in[3];
    const float* g_sp   = (const float*)d_in[4];
    const float* b_sp   = (const float*)d_in[5];
    const float* g_pp   = (const float*)d_in[6];
    const float* b_pp   = (const float*)d_in[7];
    const float* Wv     = (const float*)d_in[8];
    const float* Wo     = (const float*)d_in[9];
    const float* Wm     = (const float*)d_in[10];
    const float* bm     = (const float*)d_in[11];
    const float* Wb     = (const float*)d_in[12];
    const float* bb     = (const float*)d_in[13];

    double2* kpack = (double2*)((char*)d_ws + WS_KPACK_OFF);
    float*   Tf    = (float*)((char*)d_ws + WS_TF_OFF);
    double*  zb    = (double*)((char*)d_ws + WS_ZB_OFF);

    precompute_kernel<<<1, 256, 0, stream>>>(lookup, g_st, b_st, g_pp, b_pp,
                                             Wv, Wo, Wm, bm, Wb, bb,
                                             kpack, Tf, zb);
    hopfield_kernel<<<NBLK, 256, 0, stream>>>(x, g_sp, b_sp, kpack, Tf, zb, Wb,
                                              (float*)d_out);
}